// Round 5
// baseline (74.916 us; speedup 1.0000x reference)
//
#include <hip/hip_runtime.h>

#define BLOCK 256
#define CHUNK 256           // n-points staged per block (== BLOCK: one stage load/thread)
#define LOG2E 1.44269504088896340736f

// v(p_m) = sum_n exp(-|p_m - g_n|^2) * c_n   (SIGMA = 1)
// exp(-|p-g|^2) = exp(-|p|^2) * [exp(-|g|^2)] * exp2(2*log2e * p.g)
//
// Experiment ledger:
//   R0 (69.2us): CHUNK=256, MPT=1, memset+atomics            <- best
//   R1 (77.5us): MPT=4 @ 256 blocks  -> occupancy loss
//   R2 (77.4us): no LDS, global loads -> latency-bound
//   R3 (70.4us): partials+reduce      -> write path not the bottleneck
//   R4 (74.1us): MPT=4 @ same occupancy -> LDS traffic not the bottleneck
// Kernel A is ~20us invariant under LDS/write/load changes. Only invariant
// left: 67M exponentials on the trans pipe. This round: R0 structure exactly,
// but HALF the exps computed as a VALU polynomial (deg-4 exp2 on [-.5,.5] +
// v_ldexp) so trans and VALU pipes split the exponential work.
__device__ __forceinline__ float exp2_poly(float t) {
    // 2^t = 2^i * 2^f, i = round(t), f in [-0.5, 0.5].
    float fl = floorf(t + 0.5f);
    float f  = t - fl;
    int   i  = (int)fl;
    // Taylor of e^{f ln2} about 0, deg 4: rel err ~4e-5 on [-.5,.5].
    float p = fmaf(f, 0.0096181292f, 0.0555041087f);
    p = fmaf(f, p, 0.2402265070f);
    p = fmaf(f, p, 0.6931471806f);
    p = fmaf(f, p, 1.0f);
    return ldexpf(p, i);    // v_ldexp_f32: exact scale, graceful underflow
}

__global__ void __launch_bounds__(BLOCK)
translations_kernel(const float* __restrict__ gd,
                    const float* __restrict__ controls,
                    const float* __restrict__ points,
                    float* __restrict__ out,
                    int N, int M) {
    __shared__ float4 sg[CHUNK];

    const int tid = threadIdx.x;
    const int m  = blockIdx.x * BLOCK + tid;
    const int n0 = blockIdx.y * CHUNK;

    // Stage chunk: (gx, gy, c0*exp(-|g|^2), c1*exp(-|g|^2)); zero-pad OOB so the
    // main loop needs no tail handling (w * 0 == 0).
    {
        const int n = n0 + tid;
        if (n < N) {
            float2 g = ((const float2*)gd)[n];
            float2 c = ((const float2*)controls)[n];
            float  e = __expf(-(g.x * g.x + g.y * g.y));
            sg[tid] = make_float4(g.x, g.y, c.x * e, c.y * e);
        } else {
            sg[tid] = make_float4(0.f, 0.f, 0.f, 0.f);
        }
    }
    __syncthreads();

    if (m >= M) return;

    const float2 p  = ((const float2*)points)[m];
    const float  a0 = (2.0f * LOG2E) * p.x;
    const float  a1 = (2.0f * LOG2E) * p.y;

    float acc0 = 0.f, acc1 = 0.f;
#pragma unroll 4
    for (int j = 0; j < CHUNK; j += 2) {
        // Even pair: hardware v_exp_f32 (trans pipe).
        float4 g0 = sg[j];                      // wave-uniform addr -> LDS broadcast
        float  t0 = fmaf(a0, g0.x, a1 * g0.y);  // 2*log2e * (p . g)
        float  w0 = __builtin_amdgcn_exp2f(t0);
        acc0 = fmaf(w0, g0.z, acc0);
        acc1 = fmaf(w0, g0.w, acc1);
        // Odd pair: polynomial exp2 (VALU pipe) — splits exp load across pipes.
        float4 g1 = sg[j + 1];
        float  t1 = fmaf(a0, g1.x, a1 * g1.y);
        float  w1 = exp2_poly(t1);
        acc0 = fmaf(w1, g1.z, acc0);
        acc1 = fmaf(w1, g1.w, acc1);
    }

    const float s = __expf(-(p.x * p.x + p.y * p.y));
    atomicAdd(&out[2 * m],     acc0 * s);
    atomicAdd(&out[2 * m + 1], acc1 * s);
}

extern "C" void kernel_launch(void* const* d_in, const int* in_sizes, int n_in,
                              void* d_out, int out_size, void* d_ws, size_t ws_size,
                              hipStream_t stream) {
    const float* gd       = (const float*)d_in[0];  // [N*2]
    const float* controls = (const float*)d_in[1];  // [N*2]
    const float* points   = (const float*)d_in[2];  // [M,2]
    float* out = (float*)d_out;                     // [M,2] fp32

    const int N = in_sizes[0] / 2;
    const int M = in_sizes[2] / 2;

    // d_out is poisoned with 0xAA before every timed launch; atomics need zeros.
    hipMemsetAsync(d_out, 0, (size_t)out_size * sizeof(float), stream);

    dim3 grid((M + BLOCK - 1) / BLOCK, (N + CHUNK - 1) / CHUNK);
    translations_kernel<<<grid, dim3(BLOCK), 0, stream>>>(gd, controls, points, out, N, M);
}

// Round 6
// 69.858 us; speedup vs baseline: 1.0724x; 1.0724x over previous
//
#include <hip/hip_runtime.h>

#define BLOCK 256
#define CHUNK 128           // n-points staged per block; grid.y=32 -> 2048 blocks = 32 waves/CU (max)
#define LOG2E 1.44269504088896340736f

// v(p_m) = sum_n exp(-|p_m - g_n|^2) * c_n   (SIGMA = 1)
// exp(-|p-g|^2) = exp(-|p|^2) * [exp(-|g|^2)] * exp2(2*log2e * p.g)
//
// Experiment ledger:
//   R0 (69.2us): CHUNK=256, MPT=1, memset+atomics, 16 waves/CU   <- best
//   R1 (77.5us): MPT=4 @ 256 blocks   -> 4 waves/CU: latency exposed (+8)
//   R2 (77.4us): no LDS, global loads -> load-latency chain (+8)
//   R3 (70.4us): partials+reduce      -> write path insensitive (wash)
//   R4 (74.1us): MPT=4 @ 16 waves/CU  -> LDS traffic insensitive (wash)
//   R5 (74.9us): half exps as VALU poly -> trans pipe never saturated (+4.5)
// Both regressions were latency-exposure; all throughput knobs are dead.
// This round: the only untested direction — occupancy UP. CHUNK=128 doubles
// the grid to 2048 blocks = 8 blocks/CU = 32 waves/CU (hw max), doubling the
// wave pool that hides the ds_read -> fma -> v_exp -> fma chain. Inner loop,
// staging pattern, write path identical to R0.
__global__ void __launch_bounds__(BLOCK, 8)   // 8 waves/EU => 8 blocks/CU, caps VGPR<=64
translations_kernel(const float* __restrict__ gd,
                    const float* __restrict__ controls,
                    const float* __restrict__ points,
                    float* __restrict__ out,
                    int N, int M) {
    __shared__ float4 sg[CHUNK];

    const int tid = threadIdx.x;
    const int m  = blockIdx.x * BLOCK + tid;
    const int n0 = blockIdx.y * CHUNK;

    // Stage chunk: (gx, gy, c0*exp(-|g|^2), c1*exp(-|g|^2)); zero-pad OOB so the
    // main loop needs no tail handling (w * 0 == 0).
    if (tid < CHUNK) {
        const int n = n0 + tid;
        if (n < N) {
            float2 g = ((const float2*)gd)[n];
            float2 c = ((const float2*)controls)[n];
            float  e = __expf(-(g.x * g.x + g.y * g.y));
            sg[tid] = make_float4(g.x, g.y, c.x * e, c.y * e);
        } else {
            sg[tid] = make_float4(0.f, 0.f, 0.f, 0.f);
        }
    }
    __syncthreads();

    if (m >= M) return;

    const float2 p  = ((const float2*)points)[m];
    const float  a0 = (2.0f * LOG2E) * p.x;
    const float  a1 = (2.0f * LOG2E) * p.y;

    float acc0 = 0.f, acc1 = 0.f;
#pragma unroll 8
    for (int j = 0; j < CHUNK; ++j) {
        float4 g = sg[j];                       // wave-uniform addr -> LDS broadcast
        float  t = fmaf(a0, g.x, a1 * g.y);     // 2*log2e * (p . g)
        float  w = __builtin_amdgcn_exp2f(t);   // v_exp_f32
        acc0 = fmaf(w, g.z, acc0);
        acc1 = fmaf(w, g.w, acc1);
    }

    const float s = __expf(-(p.x * p.x + p.y * p.y));
    atomicAdd(&out[2 * m],     acc0 * s);
    atomicAdd(&out[2 * m + 1], acc1 * s);
}

extern "C" void kernel_launch(void* const* d_in, const int* in_sizes, int n_in,
                              void* d_out, int out_size, void* d_ws, size_t ws_size,
                              hipStream_t stream) {
    const float* gd       = (const float*)d_in[0];  // [N*2]
    const float* controls = (const float*)d_in[1];  // [N*2]
    const float* points   = (const float*)d_in[2];  // [M,2]
    float* out = (float*)d_out;                     // [M,2] fp32

    const int N = in_sizes[0] / 2;
    const int M = in_sizes[2] / 2;

    // d_out is poisoned with 0xAA before every timed launch; atomics need zeros.
    hipMemsetAsync(d_out, 0, (size_t)out_size * sizeof(float), stream);

    dim3 grid((M + BLOCK - 1) / BLOCK, (N + CHUNK - 1) / CHUNK);   // (64, 32)
    translations_kernel<<<grid, dim3(BLOCK), 0, stream>>>(gd, controls, points, out, N, M);
}

// Round 7
// 69.572 us; speedup vs baseline: 1.0768x; 1.0041x over previous
//
#include <hip/hip_runtime.h>

#define TB     1024          // threads/block = 16 waves; same 16 waves/CU as R0
#define WAVES  16
#define MBLK   64            // m-points per block (lane <-> m); grid = M/64 = 256 = 1 block/CU
#define SCHUNK 4096          // n-points staged per pass: 64 KB LDS (all of N in one pass here)
#define SLICE  (SCHUNK / WAVES)   // 256 n's per wave = R0's per-wave iteration count
#define LOG2E  1.44269504088896340736f

// v(p_m) = sum_n exp(-|p_m - g_n|^2) * c_n   (SIGMA = 1)
// exp(-|p-g|^2) = exp(-|p|^2) * [exp(-|g|^2)] * exp2(2*log2e * p.g)
//
// Experiment ledger (all fill-corrected vs the ~40us mandatory ws-poison fill):
//   R0 (69.2us): CHUNK=256, MPT=1, memset+atomics, 16 waves/CU   <- best
//   R1 (77.5us): 4 waves/CU            -> latency exposed (+8)
//   R2 (77.4us): in-loop global loads  -> latency exposed (+8)
//   R3 (70.4us): partials+reduce       -> write path insensitive
//   R4 (74.1us): MPT=4, same occupancy -> LDS traffic insensitive
//   R5 (74.9us): half exps as VALU poly-> trans pipe not saturated
//   R6 (69.9us): 32 waves/CU           -> occupancy saturated
// Every kernel-internal knob is exhausted; kernel ~6-12us inside a ~69us
// window dominated by the harness fill (~40us @85% HBM). Last controllable:
// DISPATCH STRUCTURE. This is a single dispatch — no memset, no atomics, no
// reduce kernel. Each block produces 64 complete out elements: 16 waves share
// the block's 64 m's (lane<->m), each wave sweeps a disjoint 256-slice of the
// full N staged in 64KB LDS (same wave-uniform broadcast inner loop as R0),
// then an in-LDS cross-wave reduce (reusing sg) and one plain store.
__global__ void __launch_bounds__(TB)
translations_fused(const float* __restrict__ gd,
                   const float* __restrict__ controls,
                   const float* __restrict__ points,
                   float* __restrict__ out,
                   int N, int M) {
    __shared__ float4 sg[SCHUNK];    // 64 KB; dead after main loop -> reused for reduce

    const int tid  = threadIdx.x;
    const int lane = tid & 63;
    const int wave = tid >> 6;
    const int m0   = blockIdx.x * MBLK;
    const int m    = m0 + lane;

    const float2 p  = (m < M) ? ((const float2*)points)[m] : make_float2(0.f, 0.f);
    const float  a0 = (2.0f * LOG2E) * p.x;
    const float  a1 = (2.0f * LOG2E) * p.y;

    float acc0 = 0.f, acc1 = 0.f;

    for (int base = 0; base < N; base += SCHUNK) {
        // Stage up to SCHUNK n's: (gx, gy, c0*e, c1*e), e = exp(-|g|^2);
        // zero-pad OOB so the main loop needs no tail handling (w * 0 == 0).
#pragma unroll
        for (int k = 0; k < SCHUNK / TB; ++k) {   // 4 per thread
            const int idx = tid + k * TB;
            const int n   = base + idx;
            if (n < N) {
                float2 g = ((const float2*)gd)[n];
                float2 c = ((const float2*)controls)[n];
                float  e = __expf(-(g.x * g.x + g.y * g.y));
                sg[idx] = make_float4(g.x, g.y, c.x * e, c.y * e);
            } else {
                sg[idx] = make_float4(0.f, 0.f, 0.f, 0.f);
            }
        }
        __syncthreads();

        // Each wave sweeps its own 256-slice; addr is wave-uniform -> broadcast.
        const int jbase = wave * SLICE;
#pragma unroll 8
        for (int j = 0; j < SLICE; ++j) {
            float4 g = sg[jbase + j];
            float  t = fmaf(a0, g.x, a1 * g.y);     // 2*log2e * (p . g)
            float  w = __builtin_amdgcn_exp2f(t);   // v_exp_f32
            acc0 = fmaf(w, g.z, acc0);
            acc1 = fmaf(w, g.w, acc1);
        }
        __syncthreads();   // sg dead for all waves before restage / reduce reuse
    }

    // Cross-wave reduce: 16 partials per m, staged in the (now dead) sg buffer.
    float* red = (float*)sg;                       // 16*64*2 floats = 8 KB
    red[(wave * MBLK + lane) * 2 + 0] = acc0;
    red[(wave * MBLK + lane) * 2 + 1] = acc1;
    __syncthreads();

    if (tid < MBLK) {                              // thread tid owns m0+tid; its p is already local (wave 0, lane=tid)
        float s0 = 0.f, s1 = 0.f;
#pragma unroll
        for (int w = 0; w < WAVES; ++w) {
            s0 += red[(w * MBLK + tid) * 2 + 0];
            s1 += red[(w * MBLK + tid) * 2 + 1];
        }
        if (m < M) {
            const float s = __expf(-(p.x * p.x + p.y * p.y));
            ((float2*)out)[m] = make_float2(s0 * s, s1 * s);   // overwrites poison; no memset needed
        }
    }
}

extern "C" void kernel_launch(void* const* d_in, const int* in_sizes, int n_in,
                              void* d_out, int out_size, void* d_ws, size_t ws_size,
                              hipStream_t stream) {
    const float* gd       = (const float*)d_in[0];  // [N*2]
    const float* controls = (const float*)d_in[1];  // [N*2]
    const float* points   = (const float*)d_in[2];  // [M,2]
    float* out = (float*)d_out;                     // [M,2] fp32

    const int N = in_sizes[0] / 2;
    const int M = in_sizes[2] / 2;

    // Single dispatch: every out element is written exactly once by its block.
    dim3 grid((M + MBLK - 1) / MBLK);               // 256 blocks = 1/CU, 16 waves/CU
    translations_fused<<<grid, dim3(TB), 0, stream>>>(gd, controls, points, out, N, M);
}